// Round 1
// baseline (526.509 us; speedup 1.0000x reference)
//
#include <hip/hip_runtime.h>

// BilateralGrid apply: out = trilinear-sliced affine(grid, coords, luminance) @ [rgb,1]
// Grid: (16,16,8,12) fp32, strides in floats: y=1536, x=96, z=12.
// One thread handles 4 consecutive pixels => all global I/O is aligned float4.

__device__ __forceinline__ float4 f4_mul(float4 a, float s) {
    return make_float4(a.x * s, a.y * s, a.z * s, a.w * s);
}
__device__ __forceinline__ float4 f4_fma(float4 a, float s, float4 c) {
    return make_float4(fmaf(a.x, s, c.x), fmaf(a.y, s, c.y),
                       fmaf(a.z, s, c.z), fmaf(a.w, s, c.w));
}

__global__ __launch_bounds__(256) void bilateral_apply(
    const float* __restrict__ pixels,
    const float* __restrict__ coords,
    const float* __restrict__ grid,
    float* __restrict__ out,
    int n4)
{
    int t = blockIdx.x * blockDim.x + threadIdx.x;
    if (t >= n4) return;
    long long base = (long long)t * 4;  // first pixel index of this thread

    // 4 pixels = 12 floats, 4 coords = 8 floats: clean float4 loads
    const float* pp = pixels + base * 3;
    const float* cp = coords + base * 2;
    float4 pa = *(const float4*)(pp + 0);
    float4 pb = *(const float4*)(pp + 4);
    float4 pc = *(const float4*)(pp + 8);
    float4 ca = *(const float4*)(cp + 0);
    float4 cb = *(const float4*)(cp + 4);

    float R[4]  = {pa.x, pa.w, pb.z, pc.y};
    float G[4]  = {pa.y, pb.x, pb.w, pc.z};
    float Bc[4] = {pa.z, pb.y, pc.x, pc.w};
    float CX[4] = {ca.x, ca.z, cb.x, cb.z};
    float CY[4] = {ca.y, ca.w, cb.y, cb.w};

    float O[12];

    #pragma unroll
    for (int k = 0; k < 4; ++k) {
        float r = R[k], g = G[k], b = Bc[k];
        float guide = 0.2126f * r + 0.7152f * g + 0.0722f * b;

        float gx = fminf(fmaxf(CX[k] * 15.0f, 0.0f), 14.999f);
        float gy = fminf(fmaxf(CY[k] * 15.0f, 0.0f), 14.999f);
        float gz = fminf(fminf(fmaxf(guide, 0.0f), 1.0f) * 7.0f, 6.999f);

        int x0 = (int)gx, y0 = (int)gy, z0 = (int)gz;  // floor (non-negative)
        float fx = gx - (float)x0;
        float fy = gy - (float)y0;
        float fz = gz - (float)z0;
        // gz <= 6.999 => z0 <= 6 => z1 = z0+1 in-bounds: z0,z1 planes are
        // 24 contiguous floats (6 aligned float4s) per (y,x) corner.

        const float* g00 = grid + y0 * 1536 + x0 * 96 + z0 * 12;
        const float4* q00 = (const float4*)g00;           // (y0,x0)
        const float4* q01 = (const float4*)(g00 + 96);    // (y0,x1)
        const float4* q10 = (const float4*)(g00 + 1536);  // (y1,x0)
        const float4* q11 = (const float4*)(g00 + 1632);  // (y1,x1)

        float wz0 = 1.0f - fz, wz1 = fz;
        float w00 = (1.0f - fy) * (1.0f - fx);
        float w01 = (1.0f - fy) * fx;
        float w10 = fy * (1.0f - fx);
        float w11 = fy * fx;

        float4 coef[3];
        #pragma unroll
        for (int i = 0; i < 3; ++i) {
            // z-lerp each corner, then bilinear-weighted sum
            float4 v00 = f4_fma(q00[i + 3], wz1, f4_mul(q00[i], wz0));
            float4 v01 = f4_fma(q01[i + 3], wz1, f4_mul(q01[i], wz0));
            float4 v10 = f4_fma(q10[i + 3], wz1, f4_mul(q10[i], wz0));
            float4 v11 = f4_fma(q11[i + 3], wz1, f4_mul(q11[i], wz0));
            float4 c = f4_mul(v00, w00);
            c = f4_fma(v01, w01, c);
            c = f4_fma(v10, w10, c);
            c = f4_fma(v11, w11, c);
            coef[i] = c;
        }

        O[3 * k + 0] = fmaf(coef[0].x, r, fmaf(coef[0].y, g, fmaf(coef[0].z, b, coef[0].w)));
        O[3 * k + 1] = fmaf(coef[1].x, r, fmaf(coef[1].y, g, fmaf(coef[1].z, b, coef[1].w)));
        O[3 * k + 2] = fmaf(coef[2].x, r, fmaf(coef[2].y, g, fmaf(coef[2].z, b, coef[2].w)));
    }

    float* op = out + base * 3;
    *(float4*)(op + 0) = make_float4(O[0], O[1], O[2],  O[3]);
    *(float4*)(op + 4) = make_float4(O[4], O[5], O[6],  O[7]);
    *(float4*)(op + 8) = make_float4(O[8], O[9], O[10], O[11]);
}

extern "C" void kernel_launch(void* const* d_in, const int* in_sizes, int n_in,
                              void* d_out, int out_size, void* d_ws, size_t ws_size,
                              hipStream_t stream) {
    const float* pixels = (const float*)d_in[0];
    const float* coords = (const float*)d_in[1];
    const float* grid   = (const float*)d_in[2];
    float* out = (float*)d_out;

    int npix = in_sizes[0] / 3;   // 8,294,400 (divisible by 4)
    int n4   = npix / 4;          // 2,073,600
    int block = 256;
    int nblk = (n4 + block - 1) / block;
    bilateral_apply<<<nblk, block, 0, stream>>>(pixels, coords, grid, out, n4);
}

// Round 2
// 254.183 us; speedup vs baseline: 2.0714x; 2.0714x over previous
//
#include <hip/hip_runtime.h>
#include <hip/hip_fp16.h>

// BilateralGrid apply. R0 finding: random coords => per-lane divergent gathers
// from the 96 KB grid serialize in L1 (~324 us of line lookups). Fix: stage the
// grid in LDS as fp16 (48 KB), gather via ds_read_b64 (per-lane parallel banks).
// Grid strides (in elements): y=1536, x=96, z=12. z1=z0+1 always (gz<=6.999),
// so each (y,x) corner's two z-planes are 24 contiguous values.

typedef __attribute__((ext_vector_type(4))) _Float16 h4;

#define NGRID 24576   // 16*16*8*12
#define BLOCK 512

__global__ __launch_bounds__(BLOCK) void bilateral_apply(
    const float* __restrict__ pixels,
    const float* __restrict__ coords,
    const float* __restrict__ grid,
    float* __restrict__ out,
    int n4)
{
    __shared__ _Float16 gl[NGRID];  // 48 KB

    // Cooperative load + fp32->fp16 convert: 6144 float4 reads, h4 LDS writes.
    {
        const float4* gsrc = (const float4*)grid;
        h4* gdst = (h4*)gl;
        for (int i = threadIdx.x; i < NGRID / 4; i += BLOCK) {
            float4 v = gsrc[i];
            h4 h = { (_Float16)v.x, (_Float16)v.y, (_Float16)v.z, (_Float16)v.w };
            gdst[i] = h;
        }
    }
    __syncthreads();

    const int stride = gridDim.x * BLOCK;
    for (int t = blockIdx.x * BLOCK + threadIdx.x; t < n4; t += stride) {
        long long base = (long long)t * 4;  // first pixel of this quad

        const float* pp = pixels + base * 3;
        const float* cp = coords + base * 2;
        float4 pa = *(const float4*)(pp + 0);
        float4 pb = *(const float4*)(pp + 4);
        float4 pc = *(const float4*)(pp + 8);
        float4 ca = *(const float4*)(cp + 0);
        float4 cb = *(const float4*)(cp + 4);

        float R[4]  = {pa.x, pa.w, pb.z, pc.y};
        float G[4]  = {pa.y, pb.x, pb.w, pc.z};
        float Bc[4] = {pa.z, pb.y, pc.x, pc.w};
        float CX[4] = {ca.x, ca.z, cb.x, cb.z};
        float CY[4] = {ca.y, ca.w, cb.y, cb.w};

        float O[12];

        #pragma unroll
        for (int k = 0; k < 4; ++k) {
            float r = R[k], g = G[k], b = Bc[k];
            float guide = 0.2126f * r + 0.7152f * g + 0.0722f * b;

            float gx = fminf(fmaxf(CX[k] * 15.0f, 0.0f), 14.999f);
            float gy = fminf(fmaxf(CY[k] * 15.0f, 0.0f), 14.999f);
            float gz = fminf(fminf(fmaxf(guide, 0.0f), 1.0f) * 7.0f, 6.999f);

            int x0 = (int)gx, y0 = (int)gy, z0 = (int)gz;
            float fx = gx - (float)x0;
            float fy = gy - (float)y0;
            float fz = gz - (float)z0;

            int cbase = y0 * 1536 + x0 * 96 + z0 * 12;
            const int coff[4] = {0, 96, 1536, 1632};  // (y0,x0),(y0,x1),(y1,x0),(y1,x1)
            float wz0 = 1.0f - fz, wz1 = fz;
            float cw[4] = {(1.0f - fy) * (1.0f - fx), (1.0f - fy) * fx,
                           fy * (1.0f - fx),           fy * fx};

            float acc[12] = {0,0,0,0,0,0,0,0,0,0,0,0};

            #pragma unroll
            for (int c = 0; c < 4; ++c) {
                const h4* q = (const h4*)(gl + cbase + coff[c]);  // 24-B multiple => 8-B aligned
                h4 a0 = q[0], a1 = q[1], a2 = q[2];  // z0 plane (12 vals)
                h4 b0 = q[3], b1 = q[4], b2 = q[5];  // z1 plane
                float u0 = cw[c] * wz0, u1 = cw[c] * wz1;
                acc[0]  = fmaf(u0, (float)a0.x, fmaf(u1, (float)b0.x, acc[0]));
                acc[1]  = fmaf(u0, (float)a0.y, fmaf(u1, (float)b0.y, acc[1]));
                acc[2]  = fmaf(u0, (float)a0.z, fmaf(u1, (float)b0.z, acc[2]));
                acc[3]  = fmaf(u0, (float)a0.w, fmaf(u1, (float)b0.w, acc[3]));
                acc[4]  = fmaf(u0, (float)a1.x, fmaf(u1, (float)b1.x, acc[4]));
                acc[5]  = fmaf(u0, (float)a1.y, fmaf(u1, (float)b1.y, acc[5]));
                acc[6]  = fmaf(u0, (float)a1.z, fmaf(u1, (float)b1.z, acc[6]));
                acc[7]  = fmaf(u0, (float)a1.w, fmaf(u1, (float)b1.w, acc[7]));
                acc[8]  = fmaf(u0, (float)a2.x, fmaf(u1, (float)b2.x, acc[8]));
                acc[9]  = fmaf(u0, (float)a2.y, fmaf(u1, (float)b2.y, acc[9]));
                acc[10] = fmaf(u0, (float)a2.z, fmaf(u1, (float)b2.z, acc[10]));
                acc[11] = fmaf(u0, (float)a2.w, fmaf(u1, (float)b2.w, acc[11]));
            }

            O[3 * k + 0] = fmaf(acc[0], r, fmaf(acc[1],  g, fmaf(acc[2],  b, acc[3])));
            O[3 * k + 1] = fmaf(acc[4], r, fmaf(acc[5],  g, fmaf(acc[6],  b, acc[7])));
            O[3 * k + 2] = fmaf(acc[8], r, fmaf(acc[9],  g, fmaf(acc[10], b, acc[11])));
        }

        float* op = out + base * 3;
        *(float4*)(op + 0) = make_float4(O[0], O[1], O[2],  O[3]);
        *(float4*)(op + 4) = make_float4(O[4], O[5], O[6],  O[7]);
        *(float4*)(op + 8) = make_float4(O[8], O[9], O[10], O[11]);
    }
}

extern "C" void kernel_launch(void* const* d_in, const int* in_sizes, int n_in,
                              void* d_out, int out_size, void* d_ws, size_t ws_size,
                              hipStream_t stream) {
    const float* pixels = (const float*)d_in[0];
    const float* coords = (const float*)d_in[1];
    const float* grid   = (const float*)d_in[2];
    float* out = (float*)d_out;

    int npix = in_sizes[0] / 3;   // 8,294,400 (divisible by 4)
    int n4   = npix / 4;          // 2,073,600 quads
    // 48 KB LDS/block => up to 3 blocks/CU at 512 thr; launch 3*256 for full residency.
    int nblk = 768;
    bilateral_apply<<<nblk, BLOCK, 0, stream>>>(pixels, coords, grid, out, n4);
}

// Round 3
// 235.954 us; speedup vs baseline: 2.2314x; 1.0773x over previous
//
#include <hip/hip_runtime.h>

// BilateralGrid apply. R1: LDS fp16 grid gather (118 us) — LDS pipe ~60%,
// VALU 34% (bloated by 96 cvt_f32_f16/px). R2: do the whole interpolation in
// packed fp16 (v_pk_fma_f16); fold trilinear weights into per-corner (u0,u1);
// convert to fp32 only for the final affine apply. LDS traffic unchanged
// (192 B/px, the floor for this precision budget).
// Grid strides (halves): y=1536, x=96, z=12; z1=z0+1 always (gz<=6.999).

typedef _Float16 h2 __attribute__((ext_vector_type(2)));
typedef _Float16 h4 __attribute__((ext_vector_type(4)));

#define NGRID 24576   // 16*16*8*12
#define BLOCK 512

__global__ __launch_bounds__(BLOCK) void bilateral_apply(
    const float* __restrict__ pixels,
    const float* __restrict__ coords,
    const float* __restrict__ grid,
    float* __restrict__ out,
    int n4)
{
    __shared__ _Float16 gl[NGRID];  // 48 KB

    // Cooperative stage: fp32 grid -> fp16 LDS.
    {
        const float4* gsrc = (const float4*)grid;
        h4* gdst = (h4*)gl;
        for (int i = threadIdx.x; i < NGRID / 4; i += BLOCK) {
            float4 v = gsrc[i];
            h4 h = { (_Float16)v.x, (_Float16)v.y, (_Float16)v.z, (_Float16)v.w };
            gdst[i] = h;
        }
    }
    __syncthreads();

    const int stride = gridDim.x * BLOCK;
    for (int t = blockIdx.x * BLOCK + threadIdx.x; t < n4; t += stride) {
        long long base = (long long)t * 4;  // first pixel of this quad

        const float* pp = pixels + base * 3;
        const float* cp = coords + base * 2;
        float4 pa = *(const float4*)(pp + 0);
        float4 pb = *(const float4*)(pp + 4);
        float4 pc = *(const float4*)(pp + 8);
        float4 ca = *(const float4*)(cp + 0);
        float4 cb = *(const float4*)(cp + 4);

        float R[4]  = {pa.x, pa.w, pb.z, pc.y};
        float G[4]  = {pa.y, pb.x, pb.w, pc.z};
        float Bc[4] = {pa.z, pb.y, pc.x, pc.w};
        float CX[4] = {ca.x, ca.z, cb.x, cb.z};
        float CY[4] = {ca.y, ca.w, cb.y, cb.w};

        float O[12];

        #pragma unroll
        for (int k = 0; k < 4; ++k) {
            float r = R[k], g = G[k], b = Bc[k];
            float guide = 0.2126f * r + 0.7152f * g + 0.0722f * b;

            float gx = fminf(fmaxf(CX[k] * 15.0f, 0.0f), 14.999f);
            float gy = fminf(fmaxf(CY[k] * 15.0f, 0.0f), 14.999f);
            float gz = fminf(fminf(fmaxf(guide, 0.0f), 1.0f) * 7.0f, 6.999f);

            int x0 = (int)gx, y0 = (int)gy, z0 = (int)gz;
            float fx = gx - (float)x0;
            float fy = gy - (float)y0;
            float fz = gz - (float)z0;

            int cbase = y0 * 1536 + x0 * 96 + z0 * 12;
            const int coff[4] = {0, 96, 1536, 1632};  // (y0,x0),(y0,x1),(y1,x0),(y1,x1)
            float wz0 = 1.0f - fz, wz1 = fz;
            float cw[4] = {(1.0f - fy) * (1.0f - fx), (1.0f - fy) * fx,
                           fy * (1.0f - fx),           fy * fx};

            h4 acc0 = (h4)(_Float16)0.0f;
            h4 acc1 = (h4)(_Float16)0.0f;
            h4 acc2 = (h4)(_Float16)0.0f;

            #pragma unroll
            for (int c = 0; c < 4; ++c) {
                const h4* q = (const h4*)(gl + cbase + coff[c]);  // 8-B aligned
                h4 a0 = q[0], a1 = q[1], a2 = q[2];  // z0 plane (12 vals)
                h4 b0 = q[3], b1 = q[4], b2 = q[5];  // z1 plane
                _Float16 u0 = (_Float16)(cw[c] * wz0);
                _Float16 u1 = (_Float16)(cw[c] * wz1);
                h4 u0v = {u0, u0, u0, u0};
                h4 u1v = {u1, u1, u1, u1};
                // acc = a*u0 + (b*u1 + acc)  -> v_pk_fma_f16 pairs
                acc0 = a0 * u0v + (b0 * u1v + acc0);
                acc1 = a1 * u0v + (b1 * u1v + acc1);
                acc2 = a2 * u0v + (b2 * u1v + acc2);
            }

            O[3 * k + 0] = fmaf((float)acc0.x, r, fmaf((float)acc0.y, g,
                           fmaf((float)acc0.z, b, (float)acc0.w)));
            O[3 * k + 1] = fmaf((float)acc1.x, r, fmaf((float)acc1.y, g,
                           fmaf((float)acc1.z, b, (float)acc1.w)));
            O[3 * k + 2] = fmaf((float)acc2.x, r, fmaf((float)acc2.y, g,
                           fmaf((float)acc2.z, b, (float)acc2.w)));
        }

        float* op = out + base * 3;
        *(float4*)(op + 0) = make_float4(O[0], O[1], O[2],  O[3]);
        *(float4*)(op + 4) = make_float4(O[4], O[5], O[6],  O[7]);
        *(float4*)(op + 8) = make_float4(O[8], O[9], O[10], O[11]);
    }
}

extern "C" void kernel_launch(void* const* d_in, const int* in_sizes, int n_in,
                              void* d_out, int out_size, void* d_ws, size_t ws_size,
                              hipStream_t stream) {
    const float* pixels = (const float*)d_in[0];
    const float* coords = (const float*)d_in[1];
    const float* grid   = (const float*)d_in[2];
    float* out = (float*)d_out;

    int npix = in_sizes[0] / 3;   // 8,294,400 (divisible by 4)
    int n4   = npix / 4;          // 2,073,600 quads
    // 48 KB LDS/block, 512 thr => 3 blocks/CU (24 waves). 768 = 3*256 CUs.
    int nblk = 768;
    bilateral_apply<<<nblk, BLOCK, 0, stream>>>(pixels, coords, grid, out, n4);
}